// Round 11
// baseline (46.029 us; speedup 1.0000x reference)
//
#include <hip/hip_runtime.h>
#include <math.h>

#define N_WIRES 13
#define DIM 8192
#define N_LAYERS 3
#define N_OUT 10
#define BATCH 512
#define NTHREADS 1024
#define NWAVES 16

typedef unsigned int u32;
typedef float v2f __attribute__((ext_vector_type(2)));
typedef __fp16 v2h __attribute__((ext_vector_type(2)));
typedef _Float16 f16x8 __attribute__((ext_vector_type(8)));
typedef float f32x4 __attribute__((ext_vector_type(4)));

__device__ __forceinline__ v2f cmul2(v2f a, v2f b) {
    return (v2f){a.x * b.x - a.y * b.y, a.x * b.y + a.y * b.x};
}
// CNOT-ring permutation (GF2-linear, verified R4-R10)
__device__ __forceinline__ constexpr int ymap(int x) {
    int t = x ^ (x >> 1); t ^= t >> 2; t ^= t >> 4; t ^= t >> 8;
    return (t & 0x0FFF) | (((t ^ (x >> 12)) & 1) << 12);
}
// bank swizzle: XOR byte bits 4,5 with col bits 1,2 (keeps 16B alignment)
__device__ __forceinline__ constexpr int sw1(int b) {
    return b ^ (((b >> 6) & 6) << 3);
}
// uint-slot of element (col, j4) in a pass layout (64B cols, v2h per complex)
__device__ __forceinline__ constexpr int slotCJ(int col, int j4) {
    return sw1(col * 64 + j4 * 4) >> 2;
}
__device__ __forceinline__ u32 packh(float x, float y) {
    return __builtin_bit_cast(u32, __builtin_amdgcn_cvt_pkrtz(x, y));
}
__device__ __forceinline__ v2f unpackh(u32 u) {
    v2h h = __builtin_bit_cast(v2h, u);
    return (v2f){(float)h.x, (float)h.y};
}
__device__ __forceinline__ v2f uent(const float4* u, int r, int c) {
    float4 q = u[r];
    return c ? (v2f){q.z, q.w} : (v2f){q.x, q.y};
}
__device__ __forceinline__ v2f dppx1(v2f v) {   // partner lane^1 (x0 bit)
    v2f r;
    r.x = __int_as_float(__builtin_amdgcn_update_dpp(0, __float_as_int(v.x), 0xB1, 0xF, 0xF, true));
    r.y = __int_as_float(__builtin_amdgcn_update_dpp(0, __float_as_int(v.y), 0xB1, 0xF, 0xF, true));
    return r;
}

__attribute__((amdgpu_num_vgpr(64)))
__global__ __launch_bounds__(NTHREADS) void vqc_kernel(
    const float* __restrict__ inputs,
    const float* __restrict__ weights,
    const float* __restrict__ embed,
    float* __restrict__ out)
{
    // state: 8192 complex as v2h in u32 slots; layout per pass: slotCJ(col, j4)
    __shared__ u32 SU[DIM];                         // 32 KB
    __shared__ u32 MU[N_LAYERS][3][512];            // 3 group-matrices/layer, 32x32 f16 row-major (18 KB)
    __shared__ float4 uu4[N_LAYERS][N_WIRES][2];
    __shared__ float co[N_LAYERS][N_WIRES];
    __shared__ float ga[N_LAYERS][N_WIRES];
    __shared__ v2f TAv[N_LAYERS][16][4];            // e^{-i(S+A'(j4,x8,x0))}, l==0 folds nrm
    __shared__ float red[NWAVES][N_OUT];

    const int b   = blockIdx.x;
    const int tid = threadIdx.x;

    // ---- setup 1: params + per-wire Rot matrices ----
    if (tid < N_LAYERS * N_WIRES) {
        const int l = tid / N_WIRES;
        const int w = tid - l * N_WIRES;
        const int base = (l * N_WIRES + w) * 3;
        const float om = embed[base + 0];
        const float bi = embed[base + 1];
        const float gm = embed[base + 2];
        co[l][w] = inputs[b * N_WIRES + w] * om + bi;
        ga[l][w] = gm;

        const float phi = weights[base + 0];
        const float th  = weights[base + 1];
        const float omg = weights[base + 2];
        float c, s, ca, sa, cb, sb;
        __sincosf(0.5f * th, &s, &c);
        __sincosf(0.5f * (phi + omg), &sa, &ca);
        __sincosf(0.5f * (phi - omg), &sb, &cb);
        uu4[l][w][0] = make_float4( ca * c, -sa * c, -cb * s, -sb * s);  // U00,U01
        uu4[l][w][1] = make_float4( cb * s, -sb * s,  ca * c,  sa * c);  // U10,U11
    }
    __syncthreads();

    // ---- setup 2: TAv phase table + Kron group matrices ----
    if (tid < N_LAYERS * 64) {
        const int ll = tid >> 6, r6 = tid & 63;
        const int j4 = r6 >> 2, p = r6 & 3;
        const int x8 = (p >> 1) & 1, x0 = p & 1;
        const int a3 = (j4 >> 3) & 1, a2 = (j4 >> 2) & 1, a1 = (j4 >> 1) & 1, a0 = j4 & 1;
        float S = 0.f;
        #pragma unroll
        for (int w = 0; w < N_WIRES; ++w) S += co[ll][w] + ga[ll][w];
        float A = S;
        if (a3) A -= 2.f * co[ll][0];
        if (a2) A -= 2.f * co[ll][1];
        if (a1) A -= 2.f * co[ll][2];
        if (a0) A -= 2.f * co[ll][3];
        if (a3 ^ a2) A -= 2.f * ga[ll][0];
        if (a2 ^ a1) A -= 2.f * ga[ll][1];
        if (a1 ^ a0) A -= 2.f * ga[ll][2];
        if (a0 ^ x8) A -= 2.f * ga[ll][3];
        if (x0 ^ a3) A -= 2.f * ga[ll][12];
        float sA, cA; __sincosf(A, &sA, &cA);
        const float sc = (ll == 0) ? 0.011048543456039806f : 1.f;  // 8192^-0.5
        TAv[ll][j4][p] = (v2f){sc * cA, -sc * sA};
    }
    // M[l][g] = interleaved real embedding of U_{4g} (x) U_{4g+1} (x) U_{4g+2} (x) U_{4g+3}
    #pragma unroll 1
    for (int it = 0; it < 3; ++it) {
        const int idx = tid + it * 1024;
        if (idx < N_LAYERS * 768) {
            const int ll = idx / 768, r = idx % 768;
            const int g = r >> 8, ab = r & 255, aa = ab >> 4, bb = ab & 15;
            const int w0 = g * 4;
            v2f e = uent(uu4[ll][w0 + 0], (aa >> 3) & 1, (bb >> 3) & 1);
            e = cmul2(e, uent(uu4[ll][w0 + 1], (aa >> 2) & 1, (bb >> 2) & 1));
            e = cmul2(e, uent(uu4[ll][w0 + 2], (aa >> 1) & 1, (bb >> 1) & 1));
            e = cmul2(e, uent(uu4[ll][w0 + 3], aa & 1, bb & 1));
            MU[ll][g][(2 * aa + 0) * 16 + bb] = packh(e.x, -e.y);   // row 2a:   ( gr, -gi)
            MU[ll][g][(2 * aa + 1) * 16 + bb] = packh(e.y,  e.x);   // row 2a+1: ( gi,  gr)
        }
    }
    __syncthreads();

    // ---- thread constants ----
    const int lane = tid & 63;
    const int wid  = tid >> 6;
    const int lg   = lane >> 4;        // k-block / D-row group
    const int ln   = lane & 15;        // frag row/col
    const int col0 = 32 * wid + ln;    // tile 2*wid
    const int col1 = col0 + 16;        // tile 2*wid+1
    const int Ymg  = ymap(lg << 2);
    const int YM2  = ymap(2), YM16 = ymap(16);
    // phase-pass mapping: thread owns col cp, j4 = 8*hp .. 8*hp+7
    const int cp = tid >> 1, hp = tid & 1;
    const int pc = (((cp >> 8) & 1) << 1) | (cp & 1);   // (x8<<1)|x0

    float accO[N_OUT];
    #pragma unroll
    for (int o = 0; o < N_OUT; ++o) accO[o] = 0.f;

    #pragma unroll 1
    for (int l = 0; l < N_LAYERS; ++l) {
        // ===== phase (layer start); l==0: init write (no read) =====
        {
            float Bang = 0.f;   // wires 4..12 Z + ZZ (4,5)..(11,12), all within bits 8..0
            if (cp & 256) Bang -= 2.f * co[l][4];
            if (cp & 128) Bang -= 2.f * co[l][5];
            if (cp & 64)  Bang -= 2.f * co[l][6];
            if (cp & 32)  Bang -= 2.f * co[l][7];
            if (cp & 16)  Bang -= 2.f * co[l][8];
            if (cp & 8)   Bang -= 2.f * co[l][9];
            if (cp & 4)   Bang -= 2.f * co[l][10];
            if (cp & 2)   Bang -= 2.f * co[l][11];
            if (cp & 1)   Bang -= 2.f * co[l][12];
            if (((cp >> 8) ^ (cp >> 7)) & 1) Bang -= 2.f * ga[l][4];
            if (((cp >> 7) ^ (cp >> 6)) & 1) Bang -= 2.f * ga[l][5];
            if (((cp >> 6) ^ (cp >> 5)) & 1) Bang -= 2.f * ga[l][6];
            if (((cp >> 5) ^ (cp >> 4)) & 1) Bang -= 2.f * ga[l][7];
            if (((cp >> 4) ^ (cp >> 3)) & 1) Bang -= 2.f * ga[l][8];
            if (((cp >> 3) ^ (cp >> 2)) & 1) Bang -= 2.f * ga[l][9];
            if (((cp >> 2) ^ (cp >> 1)) & 1) Bang -= 2.f * ga[l][10];
            if (((cp >> 1) ^  cp      ) & 1) Bang -= 2.f * ga[l][11];
            float sb, cb; __sincosf(Bang, &sb, &cb);
            const v2f Fb = {cb, -sb};
            #pragma unroll
            for (int j = 0; j < 8; ++j) {
                const int j4 = hp * 8 + j;
                const int s = slotCJ(cp, j4);
                const v2f F = cmul2(TAv[l][j4][pc], Fb);
                if (l == 0) {
                    SU[s] = packh(F.x, F.y);
                } else {
                    const v2f v = unpackh(SU[s]);
                    const v2f nv = cmul2(v, F);
                    SU[s] = packh(nv.x, nv.y);
                }
            }
        }
        __syncthreads();

        // ===== three MFMA group-passes =====
        #pragma unroll 1
        for (int gp = 0; gp < 3; ++gp) {
            const f16x8 a0 = __builtin_bit_cast(f16x8, *(const uint4*)&MU[l][gp][ln * 16 + lg * 4]);
            const f16x8 a1 = __builtin_bit_cast(f16x8, *(const uint4*)&MU[l][gp][(16 + ln) * 16 + lg * 4]);
            const f16x8 b0 = __builtin_bit_cast(f16x8, *(const uint4*)&SU[slotCJ(col0, lg * 4)]);
            const f16x8 b1 = __builtin_bit_cast(f16x8, *(const uint4*)&SU[slotCJ(col1, lg * 4)]);
            __syncthreads();   // all reads done before any relayout write

            const f32x4 zz = {0.f, 0.f, 0.f, 0.f};
            const f32x4 d00 = __builtin_amdgcn_mfma_f32_16x16x32_f16(a0, b0, zz, 0, 0, 0);
            const f32x4 d10 = __builtin_amdgcn_mfma_f32_16x16x32_f16(a1, b0, zz, 0, 0, 0);
            const f32x4 d01 = __builtin_amdgcn_mfma_f32_16x16x32_f16(a0, b1, zz, 0, 0, 0);
            const f32x4 d11 = __builtin_amdgcn_mfma_f32_16x16x32_f16(a1, b1, zz, 0, 0, 0);

            if (gp == 0) {
                // write to L2: elem (J=x12..9, c1=col) -> col2=(J<<5)|(c1&31), j2=c1>>5
                #pragma unroll
                for (int t2 = 0; t2 < 2; ++t2) {
                    const int col = t2 ? col1 : col0;
                    const f32x4 d0 = t2 ? d01 : d00;
                    const f32x4 d1 = t2 ? d11 : d10;
                    const int Dc = sw1(((col & 31) << 6) ^ (((col >> 5) & 15) << 2)) >> 2;
                    SU[Dc ^ ((2 * lg + 0) << 9)] = packh(d0[0], d0[1]);
                    SU[Dc ^ ((2 * lg + 1) << 9)] = packh(d0[2], d0[3]);
                    SU[Dc ^ ((8 + 2 * lg) << 9)] = packh(d1[0], d1[1]);
                    SU[Dc ^ ((9 + 2 * lg) << 9)] = packh(d1[2], d1[3]);
                }
            } else if (gp == 1) {
                // write to L3: elem (J2=x8..5, c2=col): col3=((c2>>5)<<4|J2)<<1|(c2&1), j3=(c2>>1)&15
                #pragma unroll
                for (int t2 = 0; t2 < 2; ++t2) {
                    const int col = t2 ? col1 : col0;
                    const f32x4 d0 = t2 ? d01 : d00;
                    const f32x4 d1 = t2 ? d11 : d10;
                    const int Dc = ((col >> 5) << 9) ^ ((col & 1) << 4) ^ ((col >> 1) & 15);
                    #pragma unroll
                    for (int jj = 0; jj < 4; ++jj) {
                        const int J2 = (jj >> 1) * 8 + 2 * lg + (jj & 1);
                        const int s = Dc ^ (J2 << 5) ^ ((J2 & 3) << 2);
                        const float xr = (jj < 2) ? d0[(jj & 1) * 2] : d1[(jj & 1) * 2];
                        const float xi = (jj < 2) ? d0[(jj & 1) * 2 + 1] : d1[(jj & 1) * 2 + 1];
                        SU[s] = packh(xr, xi);
                    }
                }
            } else {
                // P3: wire-12 DPP gate, then CNOT-scatter to next L1 (l<2) or readout (l==2)
                const float4 uA12 = uu4[l][12][0], uB12 = uu4[l][12][1];
                const bool hb = (tid & 1) != 0;
                const v2f ua = hb ? (v2f){uB12.z, uB12.w} : (v2f){uA12.x, uA12.y};
                const v2f up = hb ? (v2f){uB12.x, uB12.y} : (v2f){uA12.z, uA12.w};
                #pragma unroll
                for (int t2 = 0; t2 < 2; ++t2) {
                    const int col = t2 ? col1 : col0;
                    const f32x4 d0 = t2 ? d01 : d00;
                    const f32x4 d1 = t2 ? d11 : d10;
                    v2f vv[4] = {{d0[0], d0[1]}, {d0[2], d0[3]}, {d1[0], d1[1]}, {d1[2], d1[3]}};
                    #pragma unroll
                    for (int jj = 0; jj < 4; ++jj) {
                        const v2f pp = dppx1(vv[jj]);
                        vv[jj] = cmul2(ua, vv[jj]) + cmul2(up, pp);
                    }
                    const int Yc = ymap(((col >> 1) << 5) | (col & 1)) ^ Ymg;
                    const int cadd[4] = {0, YM2, YM16, YM16 ^ YM2};
                    if (l < N_LAYERS - 1) {
                        #pragma unroll
                        for (int jj = 0; jj < 4; ++jj) {
                            const int y = Yc ^ cadd[jj];
                            SU[sw1(((y & 511) << 6) ^ ((y >> 9) << 2)) >> 2] = packh(vv[jj].x, vv[jj].y);
                        }
                    } else {
                        #pragma unroll
                        for (int jj = 0; jj < 4; ++jj) {
                            const int y = Yc ^ cadd[jj];
                            const float pw = vv[jj].x * vv[jj].x + vv[jj].y * vv[jj].y;
                            #pragma unroll
                            for (int o = 0; o < N_OUT; ++o)
                                accO[o] += ((y >> (12 - o)) & 1) ? -pw : pw;
                        }
                    }
                }
            }
            __syncthreads();
        }
    }

    // ---- block reduce + output ----
    #pragma unroll
    for (int off = 32; off >= 1; off >>= 1) {
        #pragma unroll
        for (int o = 0; o < N_OUT; ++o) accO[o] += __shfl_down(accO[o], off);
    }
    if (lane == 0) {
        #pragma unroll
        for (int o = 0; o < N_OUT; ++o) red[wid][o] = accO[o];
    }
    __syncthreads();
    if (tid < N_OUT) {
        float s = 0.f;
        #pragma unroll
        for (int w = 0; w < NWAVES; ++w) s += red[w][tid];
        out[b * N_OUT + tid] = s;
    }
}

extern "C" void kernel_launch(void* const* d_in, const int* in_sizes, int n_in,
                              void* d_out, int out_size, void* d_ws, size_t ws_size,
                              hipStream_t stream) {
    const float* inputs  = (const float*)d_in[0];
    const float* weights = (const float*)d_in[1];
    const float* embed   = (const float*)d_in[2];
    float* out = (float*)d_out;
    vqc_kernel<<<BATCH, NTHREADS, 0, stream>>>(inputs, weights, embed, out);
}

// Round 12
// 46.023 us; speedup vs baseline: 1.0001x; 1.0001x over previous
//
#include <hip/hip_runtime.h>
#include <math.h>

#define N_WIRES 13
#define DIM 8192
#define N_LAYERS 3
#define N_OUT 10
#define BATCH 512
#define NTHREADS 1024
#define NWAVES 16

typedef unsigned int u32;
typedef float v2f __attribute__((ext_vector_type(2)));
typedef __fp16 v2h __attribute__((ext_vector_type(2)));
typedef _Float16 f16x8 __attribute__((ext_vector_type(8)));
typedef float f32x4 __attribute__((ext_vector_type(4)));

__device__ __forceinline__ v2f cmul2(v2f a, v2f b) {
    return (v2f){a.x * b.x - a.y * b.y, a.x * b.y + a.y * b.x};
}
// CNOT-ring permutation (GF2-linear, verified R4-R10)
__device__ __forceinline__ constexpr int ymap(int x) {
    int t = x ^ (x >> 1); t ^= t >> 2; t ^= t >> 4; t ^= t >> 8;
    return (t & 0x0FFF) | (((t ^ (x >> 12)) & 1) << 12);
}
// bank swizzle: XOR byte bits 4,5 with col bits 1,2 (keeps 16B alignment)
__device__ __forceinline__ constexpr int sw1(int b) {
    return b ^ (((b >> 6) & 6) << 3);
}
// uint-slot of element (col, j4) in a pass layout (64B cols, v2h per complex)
__device__ __forceinline__ constexpr int slotCJ(int col, int j4) {
    return sw1(col * 64 + j4 * 4) >> 2;
}
__device__ __forceinline__ u32 packh(float x, float y) {
    return __builtin_bit_cast(u32, __builtin_amdgcn_cvt_pkrtz(x, y));
}
__device__ __forceinline__ v2f unpackh(u32 u) {
    v2h h = __builtin_bit_cast(v2h, u);
    return (v2f){(float)h.x, (float)h.y};
}
__device__ __forceinline__ v2f uent(const float4* u, int r, int c) {
    float4 q = u[r];
    return c ? (v2f){q.z, q.w} : (v2f){q.x, q.y};
}
__device__ __forceinline__ v2f dppx1(v2f v) {   // partner lane^1 (x0 bit)
    v2f r;
    r.x = __int_as_float(__builtin_amdgcn_update_dpp(0, __float_as_int(v.x), 0xB1, 0xF, 0xF, true));
    r.y = __int_as_float(__builtin_amdgcn_update_dpp(0, __float_as_int(v.y), 0xB1, 0xF, 0xF, true));
    return r;
}

__attribute__((amdgpu_num_vgpr(64)))
__global__ __launch_bounds__(NTHREADS) void vqc_kernel(
    const float* __restrict__ inputs,
    const float* __restrict__ weights,
    const float* __restrict__ embed,
    float* __restrict__ out)
{
    // state: 8192 complex as v2h in u32 slots; layout per pass: slotCJ(col, j4)
    __shared__ u32 SU[DIM];                         // 32 KB
    __shared__ u32 MU[N_LAYERS][3][512];            // 3 group-matrices/layer, 32x32 f16 row-major (18 KB)
    __shared__ float4 uu4[N_LAYERS][N_WIRES][2];
    __shared__ float co[N_LAYERS][N_WIRES];
    __shared__ float ga[N_LAYERS][N_WIRES];
    __shared__ v2f TAv[N_LAYERS][16][4];            // e^{-i(S+A'(j4,x8,x0))}, l==0 folds nrm
    __shared__ float red[NWAVES][N_OUT];

    const int b   = blockIdx.x;
    const int tid = threadIdx.x;

    // ---- setup 1: params + per-wire Rot matrices ----
    if (tid < N_LAYERS * N_WIRES) {
        const int l = tid / N_WIRES;
        const int w = tid - l * N_WIRES;
        const int base = (l * N_WIRES + w) * 3;
        const float om = embed[base + 0];
        const float bi = embed[base + 1];
        const float gm = embed[base + 2];
        co[l][w] = inputs[b * N_WIRES + w] * om + bi;
        ga[l][w] = gm;

        const float phi = weights[base + 0];
        const float th  = weights[base + 1];
        const float omg = weights[base + 2];
        float c, s, ca, sa, cb, sb;
        __sincosf(0.5f * th, &s, &c);
        __sincosf(0.5f * (phi + omg), &sa, &ca);
        __sincosf(0.5f * (phi - omg), &sb, &cb);
        uu4[l][w][0] = make_float4( ca * c, -sa * c, -cb * s, -sb * s);  // U00,U01
        uu4[l][w][1] = make_float4( cb * s, -sb * s,  ca * c,  sa * c);  // U10,U11
    }
    __syncthreads();

    // ---- setup 2: TAv phase table + Kron group matrices ----
    if (tid < N_LAYERS * 64) {
        const int ll = tid >> 6, r6 = tid & 63;
        const int j4 = r6 >> 2, p = r6 & 3;
        const int x8 = (p >> 1) & 1, x0 = p & 1;
        const int a3 = (j4 >> 3) & 1, a2 = (j4 >> 2) & 1, a1 = (j4 >> 1) & 1, a0 = j4 & 1;
        float S = 0.f;
        #pragma unroll
        for (int w = 0; w < N_WIRES; ++w) S += co[ll][w] + ga[ll][w];
        float A = S;
        if (a3) A -= 2.f * co[ll][0];
        if (a2) A -= 2.f * co[ll][1];
        if (a1) A -= 2.f * co[ll][2];
        if (a0) A -= 2.f * co[ll][3];
        if (a3 ^ a2) A -= 2.f * ga[ll][0];
        if (a2 ^ a1) A -= 2.f * ga[ll][1];
        if (a1 ^ a0) A -= 2.f * ga[ll][2];
        if (a0 ^ x8) A -= 2.f * ga[ll][3];
        if (x0 ^ a3) A -= 2.f * ga[ll][12];
        float sA, cA; __sincosf(A, &sA, &cA);
        const float sc = (ll == 0) ? 0.011048543456039806f : 1.f;  // 8192^-0.5
        TAv[ll][j4][p] = (v2f){sc * cA, -sc * sA};
    }
    // M[l][g] = interleaved real embedding of U_{4g} (x) U_{4g+1} (x) U_{4g+2} (x) U_{4g+3}
    #pragma unroll 1
    for (int it = 0; it < 3; ++it) {
        const int idx = tid + it * 1024;
        if (idx < N_LAYERS * 768) {
            const int ll = idx / 768, r = idx % 768;
            const int g = r >> 8, ab = r & 255, aa = ab >> 4, bb = ab & 15;
            const int w0 = g * 4;
            v2f e = uent(uu4[ll][w0 + 0], (aa >> 3) & 1, (bb >> 3) & 1);
            e = cmul2(e, uent(uu4[ll][w0 + 1], (aa >> 2) & 1, (bb >> 2) & 1));
            e = cmul2(e, uent(uu4[ll][w0 + 2], (aa >> 1) & 1, (bb >> 1) & 1));
            e = cmul2(e, uent(uu4[ll][w0 + 3], aa & 1, bb & 1));
            MU[ll][g][(2 * aa + 0) * 16 + bb] = packh(e.x, -e.y);   // row 2a:   ( gr, -gi)
            MU[ll][g][(2 * aa + 1) * 16 + bb] = packh(e.y,  e.x);   // row 2a+1: ( gi,  gr)
        }
    }
    __syncthreads();

    // ---- thread constants ----
    const int lane = tid & 63;
    const int wid  = tid >> 6;
    const int lg   = lane >> 4;        // k-block / D-row group
    const int ln   = lane & 15;        // frag row/col
    const int col0 = 32 * wid + ln;    // tile 2*wid
    const int col1 = col0 + 16;        // tile 2*wid+1
    const int Ymg  = ymap(lg << 2);
    const int YM2  = ymap(2), YM16 = ymap(16);
    // phase-pass mapping: thread owns col cp, j4 = 8*hp .. 8*hp+7
    const int cp = tid >> 1, hp = tid & 1;
    const int pc = (((cp >> 8) & 1) << 1) | (cp & 1);   // (x8<<1)|x0

    float accO[N_OUT];
    #pragma unroll
    for (int o = 0; o < N_OUT; ++o) accO[o] = 0.f;

    #pragma unroll 1
    for (int l = 0; l < N_LAYERS; ++l) {
        // ===== phase (layer start); l==0: init write (no read) =====
        {
            float Bang = 0.f;   // wires 4..12 Z + ZZ (4,5)..(11,12), all within bits 8..0
            if (cp & 256) Bang -= 2.f * co[l][4];
            if (cp & 128) Bang -= 2.f * co[l][5];
            if (cp & 64)  Bang -= 2.f * co[l][6];
            if (cp & 32)  Bang -= 2.f * co[l][7];
            if (cp & 16)  Bang -= 2.f * co[l][8];
            if (cp & 8)   Bang -= 2.f * co[l][9];
            if (cp & 4)   Bang -= 2.f * co[l][10];
            if (cp & 2)   Bang -= 2.f * co[l][11];
            if (cp & 1)   Bang -= 2.f * co[l][12];
            if (((cp >> 8) ^ (cp >> 7)) & 1) Bang -= 2.f * ga[l][4];
            if (((cp >> 7) ^ (cp >> 6)) & 1) Bang -= 2.f * ga[l][5];
            if (((cp >> 6) ^ (cp >> 5)) & 1) Bang -= 2.f * ga[l][6];
            if (((cp >> 5) ^ (cp >> 4)) & 1) Bang -= 2.f * ga[l][7];
            if (((cp >> 4) ^ (cp >> 3)) & 1) Bang -= 2.f * ga[l][8];
            if (((cp >> 3) ^ (cp >> 2)) & 1) Bang -= 2.f * ga[l][9];
            if (((cp >> 2) ^ (cp >> 1)) & 1) Bang -= 2.f * ga[l][10];
            if (((cp >> 1) ^  cp      ) & 1) Bang -= 2.f * ga[l][11];
            float sb, cb; __sincosf(Bang, &sb, &cb);
            const v2f Fb = {cb, -sb};
            #pragma unroll
            for (int j = 0; j < 8; ++j) {
                const int j4 = hp * 8 + j;
                const int s = slotCJ(cp, j4);
                const v2f F = cmul2(TAv[l][j4][pc], Fb);
                if (l == 0) {
                    SU[s] = packh(F.x, F.y);
                } else {
                    const v2f v = unpackh(SU[s]);
                    const v2f nv = cmul2(v, F);
                    SU[s] = packh(nv.x, nv.y);
                }
            }
        }
        __syncthreads();

        // ===== three MFMA group-passes =====
        #pragma unroll 1
        for (int gp = 0; gp < 3; ++gp) {
            const f16x8 a0 = __builtin_bit_cast(f16x8, *(const uint4*)&MU[l][gp][ln * 16 + lg * 4]);
            const f16x8 a1 = __builtin_bit_cast(f16x8, *(const uint4*)&MU[l][gp][(16 + ln) * 16 + lg * 4]);
            const f16x8 b0 = __builtin_bit_cast(f16x8, *(const uint4*)&SU[slotCJ(col0, lg * 4)]);
            const f16x8 b1 = __builtin_bit_cast(f16x8, *(const uint4*)&SU[slotCJ(col1, lg * 4)]);
            __syncthreads();   // all reads done before any relayout write

            const f32x4 zz = {0.f, 0.f, 0.f, 0.f};
            const f32x4 d00 = __builtin_amdgcn_mfma_f32_16x16x32_f16(a0, b0, zz, 0, 0, 0);
            const f32x4 d10 = __builtin_amdgcn_mfma_f32_16x16x32_f16(a1, b0, zz, 0, 0, 0);
            const f32x4 d01 = __builtin_amdgcn_mfma_f32_16x16x32_f16(a0, b1, zz, 0, 0, 0);
            const f32x4 d11 = __builtin_amdgcn_mfma_f32_16x16x32_f16(a1, b1, zz, 0, 0, 0);

            if (gp == 0) {
                // write to L2: elem (J=x12..9, c1=col) -> col2=(J<<5)|(c1&31), j2=c1>>5
                #pragma unroll
                for (int t2 = 0; t2 < 2; ++t2) {
                    const int col = t2 ? col1 : col0;
                    const f32x4 d0 = t2 ? d01 : d00;
                    const f32x4 d1 = t2 ? d11 : d10;
                    const int Dc = sw1(((col & 31) << 6) ^ (((col >> 5) & 15) << 2)) >> 2;
                    SU[Dc ^ ((2 * lg + 0) << 9)] = packh(d0[0], d0[1]);
                    SU[Dc ^ ((2 * lg + 1) << 9)] = packh(d0[2], d0[3]);
                    SU[Dc ^ ((8 + 2 * lg) << 9)] = packh(d1[0], d1[1]);
                    SU[Dc ^ ((9 + 2 * lg) << 9)] = packh(d1[2], d1[3]);
                }
            } else if (gp == 1) {
                // write to L3: elem (J2=x8..5, c2=col): col3=((c2>>5)<<4|J2)<<1|(c2&1), j3=(c2>>1)&15
                #pragma unroll
                for (int t2 = 0; t2 < 2; ++t2) {
                    const int col = t2 ? col1 : col0;
                    const f32x4 d0 = t2 ? d01 : d00;
                    const f32x4 d1 = t2 ? d11 : d10;
                    const int Dc = ((col >> 5) << 9) ^ ((col & 1) << 4) ^ ((col >> 1) & 15);
                    #pragma unroll
                    for (int jj = 0; jj < 4; ++jj) {
                        const int J2 = (jj >> 1) * 8 + 2 * lg + (jj & 1);
                        const int s = Dc ^ (J2 << 5) ^ ((J2 & 3) << 2);
                        const float xr = (jj < 2) ? d0[(jj & 1) * 2] : d1[(jj & 1) * 2];
                        const float xi = (jj < 2) ? d0[(jj & 1) * 2 + 1] : d1[(jj & 1) * 2 + 1];
                        SU[s] = packh(xr, xi);
                    }
                }
            } else {
                // P3: wire-12 DPP gate, then CNOT-scatter to next L1 (l<2) or readout (l==2)
                const float4 uA12 = uu4[l][12][0], uB12 = uu4[l][12][1];
                const bool hb = (tid & 1) != 0;
                const v2f ua = hb ? (v2f){uB12.z, uB12.w} : (v2f){uA12.x, uA12.y};
                const v2f up = hb ? (v2f){uB12.x, uB12.y} : (v2f){uA12.z, uA12.w};
                #pragma unroll
                for (int t2 = 0; t2 < 2; ++t2) {
                    const int col = t2 ? col1 : col0;
                    const f32x4 d0 = t2 ? d01 : d00;
                    const f32x4 d1 = t2 ? d11 : d10;
                    v2f vv[4] = {{d0[0], d0[1]}, {d0[2], d0[3]}, {d1[0], d1[1]}, {d1[2], d1[3]}};
                    #pragma unroll
                    for (int jj = 0; jj < 4; ++jj) {
                        const v2f pp = dppx1(vv[jj]);
                        vv[jj] = cmul2(ua, vv[jj]) + cmul2(up, pp);
                    }
                    const int Yc = ymap(((col >> 1) << 5) | (col & 1)) ^ Ymg;
                    const int cadd[4] = {0, YM2, YM16, YM16 ^ YM2};
                    if (l < N_LAYERS - 1) {
                        #pragma unroll
                        for (int jj = 0; jj < 4; ++jj) {
                            const int y = Yc ^ cadd[jj];
                            SU[sw1(((y & 511) << 6) ^ ((y >> 9) << 2)) >> 2] = packh(vv[jj].x, vv[jj].y);
                        }
                    } else {
                        #pragma unroll
                        for (int jj = 0; jj < 4; ++jj) {
                            const int y = Yc ^ cadd[jj];
                            const float pw = vv[jj].x * vv[jj].x + vv[jj].y * vv[jj].y;
                            #pragma unroll
                            for (int o = 0; o < N_OUT; ++o)
                                accO[o] += ((y >> (12 - o)) & 1) ? -pw : pw;
                        }
                    }
                }
            }
            __syncthreads();
        }
    }

    // ---- block reduce + output ----
    #pragma unroll
    for (int off = 32; off >= 1; off >>= 1) {
        #pragma unroll
        for (int o = 0; o < N_OUT; ++o) accO[o] += __shfl_down(accO[o], off);
    }
    if (lane == 0) {
        #pragma unroll
        for (int o = 0; o < N_OUT; ++o) red[wid][o] = accO[o];
    }
    __syncthreads();
    if (tid < N_OUT) {
        float s = 0.f;
        #pragma unroll
        for (int w = 0; w < NWAVES; ++w) s += red[w][tid];
        out[b * N_OUT + tid] = s;
    }
}

extern "C" void kernel_launch(void* const* d_in, const int* in_sizes, int n_in,
                              void* d_out, int out_size, void* d_ws, size_t ws_size,
                              hipStream_t stream) {
    const float* inputs  = (const float*)d_in[0];
    const float* weights = (const float*)d_in[1];
    const float* embed   = (const float*)d_in[2];
    float* out = (float*)d_out;
    vqc_kernel<<<BATCH, NTHREADS, 0, stream>>>(inputs, weights, embed, out);
}

// Round 13
// 45.962 us; speedup vs baseline: 1.0014x; 1.0013x over previous
//
#include <hip/hip_runtime.h>
#include <math.h>

#define N_WIRES 13
#define DIM 8192
#define N_LAYERS 3
#define N_OUT 10
#define BATCH 512
#define NTHREADS 1024
#define NWAVES 16

typedef unsigned int u32;
typedef float v2f __attribute__((ext_vector_type(2)));
typedef __fp16 v2h __attribute__((ext_vector_type(2)));
typedef _Float16 f16x8 __attribute__((ext_vector_type(8)));
typedef float f32x4 __attribute__((ext_vector_type(4)));

__device__ __forceinline__ v2f cmul2(v2f a, v2f b) {
    return (v2f){a.x * b.x - a.y * b.y, a.x * b.y + a.y * b.x};
}
// CNOT-ring permutation (GF2-linear, verified R4-R10)
__device__ __forceinline__ constexpr int ymap(int x) {
    int t = x ^ (x >> 1); t ^= t >> 2; t ^= t >> 4; t ^= t >> 8;
    return (t & 0x0FFF) | (((t ^ (x >> 12)) & 1) << 12);
}
// bank swizzle: XOR byte bits 4,5 with col bits 1,2 (keeps 16B alignment)
__device__ __forceinline__ constexpr int sw1(int b) {
    return b ^ (((b >> 6) & 6) << 3);
}
// uint-slot of element (col, j4) in a pass layout (64B cols, v2h per complex)
__device__ __forceinline__ constexpr int slotCJ(int col, int j4) {
    return sw1(col * 64 + j4 * 4) >> 2;
}
__device__ __forceinline__ u32 packh(float x, float y) {
    return __builtin_bit_cast(u32, __builtin_amdgcn_cvt_pkrtz(x, y));
}
__device__ __forceinline__ v2f unpackh(u32 u) {
    v2h h = __builtin_bit_cast(v2h, u);
    return (v2f){(float)h.x, (float)h.y};
}
__device__ __forceinline__ v2f uent(const float4* u, int r, int c) {
    float4 q = u[r];
    return c ? (v2f){q.z, q.w} : (v2f){q.x, q.y};
}
__device__ __forceinline__ v2f dppx1(v2f v) {   // partner lane^1 (x0 bit)
    v2f r;
    r.x = __int_as_float(__builtin_amdgcn_update_dpp(0, __float_as_int(v.x), 0xB1, 0xF, 0xF, true));
    r.y = __int_as_float(__builtin_amdgcn_update_dpp(0, __float_as_int(v.y), 0xB1, 0xF, 0xF, true));
    return r;
}

__attribute__((amdgpu_num_vgpr(64)))
__global__ __launch_bounds__(NTHREADS) void vqc_kernel(
    const float* __restrict__ inputs,
    const float* __restrict__ weights,
    const float* __restrict__ embed,
    float* __restrict__ out)
{
    // state: 8192 complex as v2h in u32 slots; layout per pass: slotCJ(col, j4)
    __shared__ u32 SU[DIM];                         // 32 KB
    __shared__ u32 MU[N_LAYERS][3][512];            // 3 group-matrices/layer, 32x32 f16 row-major (18 KB)
    __shared__ float4 uu4[N_LAYERS][N_WIRES][2];
    __shared__ float co[N_LAYERS][N_WIRES];
    __shared__ float ga[N_LAYERS][N_WIRES];
    __shared__ v2f TAv[N_LAYERS][16][4];            // e^{-i(S+A'(j4,x8,x0))}, l==0 folds nrm
    __shared__ float red[NWAVES][N_OUT];

    const int b   = blockIdx.x;
    const int tid = threadIdx.x;

    // ---- setup 1: params + per-wire Rot matrices ----
    if (tid < N_LAYERS * N_WIRES) {
        const int l = tid / N_WIRES;
        const int w = tid - l * N_WIRES;
        const int base = (l * N_WIRES + w) * 3;
        const float om = embed[base + 0];
        const float bi = embed[base + 1];
        const float gm = embed[base + 2];
        co[l][w] = inputs[b * N_WIRES + w] * om + bi;
        ga[l][w] = gm;

        const float phi = weights[base + 0];
        const float th  = weights[base + 1];
        const float omg = weights[base + 2];
        float c, s, ca, sa, cb, sb;
        __sincosf(0.5f * th, &s, &c);
        __sincosf(0.5f * (phi + omg), &sa, &ca);
        __sincosf(0.5f * (phi - omg), &sb, &cb);
        uu4[l][w][0] = make_float4( ca * c, -sa * c, -cb * s, -sb * s);  // U00,U01
        uu4[l][w][1] = make_float4( cb * s, -sb * s,  ca * c,  sa * c);  // U10,U11
    }
    __syncthreads();

    // ---- setup 2: TAv phase table + Kron group matrices ----
    if (tid < N_LAYERS * 64) {
        const int ll = tid >> 6, r6 = tid & 63;
        const int j4 = r6 >> 2, p = r6 & 3;
        const int x8 = (p >> 1) & 1, x0 = p & 1;
        const int a3 = (j4 >> 3) & 1, a2 = (j4 >> 2) & 1, a1 = (j4 >> 1) & 1, a0 = j4 & 1;
        float S = 0.f;
        #pragma unroll
        for (int w = 0; w < N_WIRES; ++w) S += co[ll][w] + ga[ll][w];
        float A = S;
        if (a3) A -= 2.f * co[ll][0];
        if (a2) A -= 2.f * co[ll][1];
        if (a1) A -= 2.f * co[ll][2];
        if (a0) A -= 2.f * co[ll][3];
        if (a3 ^ a2) A -= 2.f * ga[ll][0];
        if (a2 ^ a1) A -= 2.f * ga[ll][1];
        if (a1 ^ a0) A -= 2.f * ga[ll][2];
        if (a0 ^ x8) A -= 2.f * ga[ll][3];
        if (x0 ^ a3) A -= 2.f * ga[ll][12];
        float sA, cA; __sincosf(A, &sA, &cA);
        const float sc = (ll == 0) ? 0.011048543456039806f : 1.f;  // 8192^-0.5
        TAv[ll][j4][p] = (v2f){sc * cA, -sc * sA};
    }
    // M[l][g] = interleaved real embedding of U_{4g} (x) U_{4g+1} (x) U_{4g+2} (x) U_{4g+3}
    #pragma unroll 1
    for (int it = 0; it < 3; ++it) {
        const int idx = tid + it * 1024;
        if (idx < N_LAYERS * 768) {
            const int ll = idx / 768, r = idx % 768;
            const int g = r >> 8, ab = r & 255, aa = ab >> 4, bb = ab & 15;
            const int w0 = g * 4;
            v2f e = uent(uu4[ll][w0 + 0], (aa >> 3) & 1, (bb >> 3) & 1);
            e = cmul2(e, uent(uu4[ll][w0 + 1], (aa >> 2) & 1, (bb >> 2) & 1));
            e = cmul2(e, uent(uu4[ll][w0 + 2], (aa >> 1) & 1, (bb >> 1) & 1));
            e = cmul2(e, uent(uu4[ll][w0 + 3], aa & 1, bb & 1));
            MU[ll][g][(2 * aa + 0) * 16 + bb] = packh(e.x, -e.y);   // row 2a:   ( gr, -gi)
            MU[ll][g][(2 * aa + 1) * 16 + bb] = packh(e.y,  e.x);   // row 2a+1: ( gi,  gr)
        }
    }
    __syncthreads();

    // ---- thread constants ----
    const int lane = tid & 63;
    const int wid  = tid >> 6;
    const int lg   = lane >> 4;        // k-block / D-row group
    const int ln   = lane & 15;        // frag row/col
    const int col0 = 32 * wid + ln;    // tile 2*wid
    const int col1 = col0 + 16;        // tile 2*wid+1
    const int Ymg  = ymap(lg << 2);
    const int YM2  = ymap(2), YM16 = ymap(16);
    // phase-pass mapping: thread owns col cp, j4 = 8*hp .. 8*hp+7
    const int cp = tid >> 1, hp = tid & 1;
    const int pc = (((cp >> 8) & 1) << 1) | (cp & 1);   // (x8<<1)|x0

    float accO[N_OUT];
    #pragma unroll
    for (int o = 0; o < N_OUT; ++o) accO[o] = 0.f;

    #pragma unroll 1
    for (int l = 0; l < N_LAYERS; ++l) {
        // ===== phase (layer start); l==0: init write (no read) =====
        {
            float Bang = 0.f;   // wires 4..12 Z + ZZ (4,5)..(11,12), all within bits 8..0
            if (cp & 256) Bang -= 2.f * co[l][4];
            if (cp & 128) Bang -= 2.f * co[l][5];
            if (cp & 64)  Bang -= 2.f * co[l][6];
            if (cp & 32)  Bang -= 2.f * co[l][7];
            if (cp & 16)  Bang -= 2.f * co[l][8];
            if (cp & 8)   Bang -= 2.f * co[l][9];
            if (cp & 4)   Bang -= 2.f * co[l][10];
            if (cp & 2)   Bang -= 2.f * co[l][11];
            if (cp & 1)   Bang -= 2.f * co[l][12];
            if (((cp >> 8) ^ (cp >> 7)) & 1) Bang -= 2.f * ga[l][4];
            if (((cp >> 7) ^ (cp >> 6)) & 1) Bang -= 2.f * ga[l][5];
            if (((cp >> 6) ^ (cp >> 5)) & 1) Bang -= 2.f * ga[l][6];
            if (((cp >> 5) ^ (cp >> 4)) & 1) Bang -= 2.f * ga[l][7];
            if (((cp >> 4) ^ (cp >> 3)) & 1) Bang -= 2.f * ga[l][8];
            if (((cp >> 3) ^ (cp >> 2)) & 1) Bang -= 2.f * ga[l][9];
            if (((cp >> 2) ^ (cp >> 1)) & 1) Bang -= 2.f * ga[l][10];
            if (((cp >> 1) ^  cp      ) & 1) Bang -= 2.f * ga[l][11];
            float sb, cb; __sincosf(Bang, &sb, &cb);
            const v2f Fb = {cb, -sb};
            #pragma unroll
            for (int j = 0; j < 8; ++j) {
                const int j4 = hp * 8 + j;
                const int s = slotCJ(cp, j4);
                const v2f F = cmul2(TAv[l][j4][pc], Fb);
                if (l == 0) {
                    SU[s] = packh(F.x, F.y);
                } else {
                    const v2f v = unpackh(SU[s]);
                    const v2f nv = cmul2(v, F);
                    SU[s] = packh(nv.x, nv.y);
                }
            }
        }
        __syncthreads();

        // ===== three MFMA group-passes =====
        #pragma unroll 1
        for (int gp = 0; gp < 3; ++gp) {
            const f16x8 a0 = __builtin_bit_cast(f16x8, *(const uint4*)&MU[l][gp][ln * 16 + lg * 4]);
            const f16x8 a1 = __builtin_bit_cast(f16x8, *(const uint4*)&MU[l][gp][(16 + ln) * 16 + lg * 4]);
            const f16x8 b0 = __builtin_bit_cast(f16x8, *(const uint4*)&SU[slotCJ(col0, lg * 4)]);
            const f16x8 b1 = __builtin_bit_cast(f16x8, *(const uint4*)&SU[slotCJ(col1, lg * 4)]);
            __syncthreads();   // all reads done before any relayout write

            const f32x4 zz = {0.f, 0.f, 0.f, 0.f};
            const f32x4 d00 = __builtin_amdgcn_mfma_f32_16x16x32_f16(a0, b0, zz, 0, 0, 0);
            const f32x4 d10 = __builtin_amdgcn_mfma_f32_16x16x32_f16(a1, b0, zz, 0, 0, 0);
            const f32x4 d01 = __builtin_amdgcn_mfma_f32_16x16x32_f16(a0, b1, zz, 0, 0, 0);
            const f32x4 d11 = __builtin_amdgcn_mfma_f32_16x16x32_f16(a1, b1, zz, 0, 0, 0);

            if (gp == 0) {
                // write to L2: elem (J=x12..9, c1=col) -> col2=(J<<5)|(c1&31), j2=c1>>5
                #pragma unroll
                for (int t2 = 0; t2 < 2; ++t2) {
                    const int col = t2 ? col1 : col0;
                    const f32x4 d0 = t2 ? d01 : d00;
                    const f32x4 d1 = t2 ? d11 : d10;
                    const int Dc = sw1(((col & 31) << 6) ^ (((col >> 5) & 15) << 2)) >> 2;
                    SU[Dc ^ ((2 * lg + 0) << 9)] = packh(d0[0], d0[1]);
                    SU[Dc ^ ((2 * lg + 1) << 9)] = packh(d0[2], d0[3]);
                    SU[Dc ^ ((8 + 2 * lg) << 9)] = packh(d1[0], d1[1]);
                    SU[Dc ^ ((9 + 2 * lg) << 9)] = packh(d1[2], d1[3]);
                }
            } else if (gp == 1) {
                // write to L3: elem (J2=x8..5, c2=col): col3=((c2>>5)<<4|J2)<<1|(c2&1), j3=(c2>>1)&15
                #pragma unroll
                for (int t2 = 0; t2 < 2; ++t2) {
                    const int col = t2 ? col1 : col0;
                    const f32x4 d0 = t2 ? d01 : d00;
                    const f32x4 d1 = t2 ? d11 : d10;
                    const int Dc = ((col >> 5) << 9) ^ ((col & 1) << 4) ^ ((col >> 1) & 15);
                    #pragma unroll
                    for (int jj = 0; jj < 4; ++jj) {
                        const int J2 = (jj >> 1) * 8 + 2 * lg + (jj & 1);
                        const int s = Dc ^ (J2 << 5) ^ ((J2 & 3) << 2);
                        const float xr = (jj < 2) ? d0[(jj & 1) * 2] : d1[(jj & 1) * 2];
                        const float xi = (jj < 2) ? d0[(jj & 1) * 2 + 1] : d1[(jj & 1) * 2 + 1];
                        SU[s] = packh(xr, xi);
                    }
                }
            } else {
                // P3: wire-12 DPP gate, then CNOT-scatter to next L1 (l<2) or readout (l==2)
                const float4 uA12 = uu4[l][12][0], uB12 = uu4[l][12][1];
                const bool hb = (tid & 1) != 0;
                const v2f ua = hb ? (v2f){uB12.z, uB12.w} : (v2f){uA12.x, uA12.y};
                const v2f up = hb ? (v2f){uB12.x, uB12.y} : (v2f){uA12.z, uA12.w};
                #pragma unroll
                for (int t2 = 0; t2 < 2; ++t2) {
                    const int col = t2 ? col1 : col0;
                    const f32x4 d0 = t2 ? d01 : d00;
                    const f32x4 d1 = t2 ? d11 : d10;
                    v2f vv[4] = {{d0[0], d0[1]}, {d0[2], d0[3]}, {d1[0], d1[1]}, {d1[2], d1[3]}};
                    #pragma unroll
                    for (int jj = 0; jj < 4; ++jj) {
                        const v2f pp = dppx1(vv[jj]);
                        vv[jj] = cmul2(ua, vv[jj]) + cmul2(up, pp);
                    }
                    const int Yc = ymap(((col >> 1) << 5) | (col & 1)) ^ Ymg;
                    const int cadd[4] = {0, YM2, YM16, YM16 ^ YM2};
                    if (l < N_LAYERS - 1) {
                        #pragma unroll
                        for (int jj = 0; jj < 4; ++jj) {
                            const int y = Yc ^ cadd[jj];
                            SU[sw1(((y & 511) << 6) ^ ((y >> 9) << 2)) >> 2] = packh(vv[jj].x, vv[jj].y);
                        }
                    } else {
                        #pragma unroll
                        for (int jj = 0; jj < 4; ++jj) {
                            const int y = Yc ^ cadd[jj];
                            const float pw = vv[jj].x * vv[jj].x + vv[jj].y * vv[jj].y;
                            #pragma unroll
                            for (int o = 0; o < N_OUT; ++o)
                                accO[o] += ((y >> (12 - o)) & 1) ? -pw : pw;
                        }
                    }
                }
            }
            __syncthreads();
        }
    }

    // ---- block reduce + output ----
    #pragma unroll
    for (int off = 32; off >= 1; off >>= 1) {
        #pragma unroll
        for (int o = 0; o < N_OUT; ++o) accO[o] += __shfl_down(accO[o], off);
    }
    if (lane == 0) {
        #pragma unroll
        for (int o = 0; o < N_OUT; ++o) red[wid][o] = accO[o];
    }
    __syncthreads();
    if (tid < N_OUT) {
        float s = 0.f;
        #pragma unroll
        for (int w = 0; w < NWAVES; ++w) s += red[w][tid];
        out[b * N_OUT + tid] = s;
    }
}

extern "C" void kernel_launch(void* const* d_in, const int* in_sizes, int n_in,
                              void* d_out, int out_size, void* d_ws, size_t ws_size,
                              hipStream_t stream) {
    const float* inputs  = (const float*)d_in[0];
    const float* weights = (const float*)d_in[1];
    const float* embed   = (const float*)d_in[2];
    float* out = (float*)d_out;
    vqc_kernel<<<BATCH, NTHREADS, 0, stream>>>(inputs, weights, embed, out);
}